// Round 10
// baseline (8500.268 us; speedup 1.0000x reference)
//
#include <hip/hip_runtime.h>

typedef _Float16 f16x8 __attribute__((ext_vector_type(8)));
typedef _Float16 f16x4 __attribute__((ext_vector_type(4)));
typedef float    f32x4 __attribute__((ext_vector_type(4)));

typedef const __attribute__((address_space(1))) void* gptr_t;
typedef __attribute__((address_space(3))) void* lptr_t;

__device__ __forceinline__ void gload_lds16(const void* g, void* l) {
  __builtin_amdgcn_global_load_lds((gptr_t)g, (lptr_t)l, 16, 0, 0);
}

constexpr int Bsz  = 8192;
constexpr int Nin  = 128;
constexpr int Hd   = 1024;
constexpr int Aact = 32;
constexpr int Od   = 64;
// OpenBLAS sgemm K-blocking: K=1024 -> blocks [0,384),[384,768),[768,1024),
// C = S1; C += S2; C += S3 (beta=0). Micro-kernel: one fp32 acc per output,
// k ascending within block.
constexpr int KC = 384;
// borderline window: only |h-1| < DELTA sites can differ from np's rounding
// (np's sgemm delta <~ 2e-6). ~400 of 67M events hit this.
constexpr float DELTA = 2e-5f;

// ---- digit split for exact MFMA: w = d1 + d2*2^-12 + d3*2^-24 + r, |r|<=2^-36.
// MFMA partial sums are multiples of 2^-11 bounded << 2^24*2^-11 -> fp32
// accumulation EXACT; combine in fp64.
__global__ void wsplit_kernel(const float* __restrict__ src, _Float16* __restrict__ d1,
                              _Float16* __restrict__ d2, _Float16* __restrict__ d3,
                              int R, int C) {
  __shared__ float tile[32][33];
  int c0 = blockIdx.x * 32, r0 = blockIdx.y * 32;
  for (int i = threadIdx.y; i < 32; i += 8)
    tile[i][threadIdx.x] = src[(size_t)(r0 + i) * C + c0 + threadIdx.x];
  __syncthreads();
  for (int i = threadIdx.y; i < 32; i += 8) {
    float w = tile[threadIdx.x][i];
    float m1 = rintf(w * 2048.0f);
    float q1 = m1 * (1.0f / 2048.0f);
    float r  = w - q1;
    float m2 = rintf(r * 8388608.0f);         // 2^23
    float q2 = m2 * (1.0f / 8388608.0f);
    float r2 = r - q2;
    float m3 = rintf(r2 * 34359738368.0f);    // 2^35
    size_t o = (size_t)(c0 + i) * R + r0 + threadIdx.x;
    d1[o] = (_Float16)q1;
    d2[o] = (_Float16)(m2 * (1.0f / 2048.0f));
    d3[o] = (_Float16)(m3 * (1.0f / 2048.0f));
  }
}

// ---- layer 1: EMULATE np's sgemm (K=128 < KC -> single block): sequential
// fp32 FMA over k ascending, one accumulator. Then the fp32 trajectory
// h = fl(fl(v+x)+b1); v resets to exact 0 -> pack 8 steps' spikes per byte.
__global__ __launch_bounds__(256)
void x1_kernel(const float* __restrict__ state, const float* __restrict__ w1,
               const float* __restrict__ b1, unsigned char* __restrict__ s1pack) {
  __shared__ float sA[64][129];   // [m][k], padded
  __shared__ float sB[128][32];   // [k][n]
  const int m0 = blockIdx.x * 64, n0 = blockIdx.y * 32;
  const int tid = threadIdx.x;
  for (int idx = tid; idx < 64 * 32; idx += 256) {
    int r = idx >> 5, c4 = (idx & 31) << 2;
    float4 v = *(const float4*)(state + (size_t)(m0 + r) * Nin + c4);
    sA[r][c4] = v.x; sA[r][c4 + 1] = v.y; sA[r][c4 + 2] = v.z; sA[r][c4 + 3] = v.w;
  }
  for (int idx = tid; idx < 128 * 8; idx += 256) {
    int r = idx >> 3, c4 = (idx & 7) << 2;
    *(float4*)&sB[r][c4] = *(const float4*)(w1 + (size_t)r * Hd + n0 + c4);
  }
  __syncthreads();
  const int tx = tid & 15, ty = tid >> 4;   // 16x16 threads, micro 4m x 2n
  float acc[4][2] = {};
  for (int k = 0; k < 128; ++k) {           // ASCENDING, single acc: np order
    float a[4], b[2];
#pragma unroll
    for (int i = 0; i < 4; ++i) a[i] = sA[ty * 4 + i][k];
#pragma unroll
    for (int j = 0; j < 2; ++j) b[j] = sB[k][tx * 2 + j];
#pragma unroll
    for (int i = 0; i < 4; ++i)
#pragma unroll
      for (int j = 0; j < 2; ++j) acc[i][j] = __fmaf_rn(a[i], b[j], acc[i][j]);
  }
#pragma unroll
  for (int i = 0; i < 4; ++i)
#pragma unroll
    for (int j = 0; j < 2; ++j) {
      int m = m0 + ty * 4 + i, n = n0 + tx * 2 + j;
      float x = acc[i][j];
      float bb = b1[n];
      float v = 0.0f;
      unsigned bits = 0;
#pragma unroll
      for (int t = 0; t < 8; ++t) {
        float h = __fadd_rn(__fadd_rn(v, x), bb);   // np: (v1 + G1) + b1
        if (h >= 1.0f) { bits |= (1u << t); v = 0.0f; } else { v = h; }
      }
      s1pack[(size_t)m * Hd + n] = (unsigned char)bits;
    }
}

// ---- expand step-t layer-1 spikes to f16 for MFMA A-operand
__global__ void expand_kernel(const unsigned char* __restrict__ pack,
                              _Float16* __restrict__ s1cur, int t) {
  size_t i = (size_t)blockIdx.x * 256 + threadIdx.x;   // over Bsz*Hd/4
  uchar4 p = ((const uchar4*)pack)[i];
  f16x4 s;
  s[0] = (_Float16)(float)((p.x >> t) & 1);
  s[1] = (_Float16)(float)((p.y >> t) & 1);
  s[2] = (_Float16)(float)((p.z >> t) & 1);
  s[3] = (_Float16)(float)((p.w >> t) & 1);
  ((f16x4*)s1cur)[i] = s;
}

// np-faithful G at step tau for neuron (m,n): masked ASCENDING fp32 sum of w2
// column entries (fma with s in {0,1} == exact add/skip), partials folded at
// KC boundaries exactly as OpenBLAS (C = S1; C += S_blk).
__device__ __noinline__ float np_gemm2_col(const unsigned char* __restrict__ prow,
                                           const float* __restrict__ w2, int n, int tau) {
  float G = 0.0f;
  int kb = 0;
  for (int blk = 0; kb < Hd; ++blk) {
    int kend = kb + KC; if (kend > Hd) kend = Hd;
    float S = 0.0f;
    for (int k = kb; k < kend; ++k)
      if ((prow[k] >> tau) & 1) S = __fadd_rn(S, w2[(size_t)k * Hd + n]);
    G = (blk == 0) ? S : __fadd_rn(G, S);
    kb = kend;
  }
  return G;
}

// ---- GEMM2: exact 3-digit MFMA decides non-borderline spikes (provably = np);
// borderline (|h-1| < DELTA): replay this neuron's full v2 recursion in
// np's summation order from s1pack + raw w2. v2/s2 stores take replay values.
__global__ __launch_bounds__(256, 2)
void gemm2d_kernel(const _Float16* __restrict__ s1, const _Float16* __restrict__ w2d1,
                   const _Float16* __restrict__ w2d2, const _Float16* __restrict__ w2d3,
                   const float* __restrict__ b2, float* __restrict__ v2,
                   _Float16* __restrict__ s2, int t,
                   const float* __restrict__ w2full,
                   const unsigned char* __restrict__ s1pack) {
  constexpr int K = Hd;
  __shared__ _Float16 lA[128 * 32], lB1[64 * 32], lB2[64 * 32], lB3[64 * 32];
  const int tid = threadIdx.x;
  const int m0 = blockIdx.x * 128, n0 = blockIdx.y * 64;
  const int wave = tid >> 6, lane = tid & 63, l15 = lane & 15, quad = lane >> 4;
  f32x4 acc[2][4][3] = {};
  for (int k0 = 0; k0 < K; k0 += 32) {
    __syncthreads();
#pragma unroll
    for (int it = 0; it < 2; ++it) {
      int slot = it * 256 + tid;
      int row = slot >> 2, kc = (slot & 3) << 3;
      gload_lds16(s1 + (size_t)(m0 + row) * K + k0 + kc, lA + slot * 8);
    }
    {
      int row = tid >> 2, kc = (tid & 3) << 3;
      size_t go = (size_t)(n0 + row) * K + k0 + kc;
      gload_lds16(w2d1 + go, lB1 + tid * 8);
      gload_lds16(w2d2 + go, lB2 + tid * 8);
      gload_lds16(w2d3 + go, lB3 + tid * 8);
    }
    __syncthreads();
    f16x8 af[2], bf[4][3];
#pragma unroll
    for (int i = 0; i < 2; ++i)
      af[i] = *(const f16x8*)(lA + (wave * 32 + i * 16 + l15) * 32 + quad * 8);
#pragma unroll
    for (int j = 0; j < 4; ++j) {
      int off = (j * 16 + l15) * 32 + quad * 8;
      bf[j][0] = *(const f16x8*)(lB1 + off);
      bf[j][1] = *(const f16x8*)(lB2 + off);
      bf[j][2] = *(const f16x8*)(lB3 + off);
    }
#pragma unroll
    for (int i = 0; i < 2; ++i)
#pragma unroll
      for (int j = 0; j < 4; ++j)
#pragma unroll
        for (int d = 0; d < 3; ++d)
          acc[i][j][d] = __builtin_amdgcn_mfma_f32_16x16x32_f16(af[i], bf[j][d], acc[i][j][d], 0, 0, 0);
  }
#pragma unroll
  for (int i = 0; i < 2; ++i)
#pragma unroll
    for (int j = 0; j < 4; ++j) {
      int n = n0 + j * 16 + l15;
      float bb = b2[n];
#pragma unroll
      for (int r = 0; r < 4; ++r) {
        int m = m0 + wave * 32 + i * 16 + quad * 4 + r;
        size_t idx = (size_t)m * Hd + n;
        double ge = (double)acc[i][j][0][r]
                  + (double)acc[i][j][1][r] * (1.0 / 4096.0)
                  + (double)acc[i][j][2][r] * (1.0 / 16777216.0);
        float G = (float)ge;                       // cr-fp32 of exact gemm
        float vp = (t == 0) ? 0.0f : v2[idx];
        float h = __fadd_rn(__fadd_rn(vp, G), bb); // np: (v2 + G) + b2
        bool sp;
        float vnew;
        if (__builtin_fabsf(h - 1.0f) >= DELTA) {  // decision certain == np
          sp = (h >= 1.0f);
          vnew = sp ? 0.0f : h;
        } else {
          // rare (~400/67M): replay np's v2 recursion for this neuron
          const unsigned char* prow = s1pack + (size_t)m * Hd;
          float v = 0.0f;
          sp = false;
          for (int tau = 0; tau <= t; ++tau) {
            float Gn = np_gemm2_col(prow, w2full, n, tau);
            float hn = __fadd_rn(__fadd_rn(v, Gn), bb);
            sp = (hn >= 1.0f);
            v = sp ? 0.0f : hn;
          }
          vnew = v;
        }
        v2[idx] = vnew;
        s2[idx] = (_Float16)(sp ? 1.0f : 0.0f);
      }
    }
}

// ---- GEMM3 (exact 3-digit) + fp32-replicated LIF (no thresholds downstream;
// ~1e-6 deviation from np's gemm3 rounding only shifts logp smoothly ~1e-5)
__global__ __launch_bounds__(256, 2)
void gemm3d_kernel(const _Float16* __restrict__ s2, const _Float16* __restrict__ w3d1,
                   const _Float16* __restrict__ w3d2, const _Float16* __restrict__ w3d3,
                   const float* __restrict__ b3, float* __restrict__ v3, int first) {
  constexpr int K = Hd;
  __shared__ _Float16 lA[64 * 32], lB1[64 * 32], lB2[64 * 32], lB3[64 * 32];
  const int tid = threadIdx.x;
  const int m0 = blockIdx.x * 64;
  const int wave = tid >> 6, lane = tid & 63, l15 = lane & 15, quad = lane >> 4;
  f32x4 acc[4][3] = {};
  for (int k0 = 0; k0 < K; k0 += 32) {
    __syncthreads();
    {
      int row = tid >> 2, kc = (tid & 3) << 3;
      gload_lds16(s2 + (size_t)(m0 + row) * K + k0 + kc, lA + tid * 8);
      size_t go = (size_t)row * K + k0 + kc;
      gload_lds16(w3d1 + go, lB1 + tid * 8);
      gload_lds16(w3d2 + go, lB2 + tid * 8);
      gload_lds16(w3d3 + go, lB3 + tid * 8);
    }
    __syncthreads();
    f16x8 af = *(const f16x8*)(lA + (wave * 16 + l15) * 32 + quad * 8);
    f16x8 bf[4][3];
#pragma unroll
    for (int j = 0; j < 4; ++j) {
      int off = (j * 16 + l15) * 32 + quad * 8;
      bf[j][0] = *(const f16x8*)(lB1 + off);
      bf[j][1] = *(const f16x8*)(lB2 + off);
      bf[j][2] = *(const f16x8*)(lB3 + off);
    }
#pragma unroll
    for (int j = 0; j < 4; ++j)
#pragma unroll
      for (int d = 0; d < 3; ++d)
        acc[j][d] = __builtin_amdgcn_mfma_f32_16x16x32_f16(af, bf[j][d], acc[j][d], 0, 0, 0);
  }
#pragma unroll
  for (int j = 0; j < 4; ++j) {
    int n = j * 16 + l15;
    float bb = b3[n];
#pragma unroll
    for (int r = 0; r < 4; ++r) {
      int m = m0 + wave * 16 + quad * 4 + r;
      size_t idx = (size_t)m * Od + n;
      double ge = (double)acc[j][0][r]
                + (double)acc[j][1][r] * (1.0 / 4096.0)
                + (double)acc[j][2][r] * (1.0 / 16777216.0);
      float x3 = __fadd_rn((float)ge, bb);
      float vp = first ? 0.0f : v3[idx];
      float d  = __fsub_rn(x3, vp);
      v3[idx]  = __fadd_rn(vp, __fmul_rn(d, 0.5f));
    }
  }
}

// ---- final: fp32 op sequence as numpy; tanh clamped to +/-1 at |z| >=
// 7.90531111. Established: np's tanh returned exactly +/-1 on every live
// band coord (else jax-np would exceed its 0.55 bound), and the clamp
// empirically removed the deterministic 1.25 band artifact (R8).
__global__ void final_kernel(const float* __restrict__ v3, const float* __restrict__ eps,
                             float* __restrict__ action, float* __restrict__ logp) {
  int tid = threadIdx.x;
  int row = blockIdx.x * 8 + (tid >> 5);
  int j = tid & 31;
  float mu = v3[(size_t)row * Od + j];
  float ls = v3[(size_t)row * Od + 32 + j];
  ls = fminf(fmaxf(ls, -20.0f), 2.0f);
  float sd = (float)exp((double)ls);
  float e  = eps[(size_t)row * Aact + j];
  float z  = __fadd_rn(mu, __fmul_rn(sd, e));
  float a;
  if (__builtin_fabsf(z) >= 7.90531111f) a = __builtin_copysignf(1.0f, z);
  else                                   a = (float)tanh((double)z);
  float aa = __fmul_rn(a, a);
  float u  = __fadd_rn(__fsub_rn(1.0f, aa), 1e-7f);
  float lg = (float)log((double)u);
  float l  = __fmul_rn(__fmul_rn(-0.5f, e), e);
  l = __fsub_rn(l, ls);
  l = __fsub_rn(l, 0.9189385332046727f);
  float term = __fsub_rn(l, lg);
  action[(size_t)row * Aact + j] = a;
  double lp = (double)term;
#pragma unroll
  for (int w = 16; w >= 1; w >>= 1) lp += __shfl_xor(lp, w);
  if (j == 0) logp[row] = (float)lp;
}

extern "C" void kernel_launch(void* const* d_in, const int* in_sizes, int n_in,
                              void* d_out, int out_size, void* d_ws, size_t ws_size,
                              hipStream_t stream) {
  const float* state = (const float*)d_in[0];
  const float* w1 = (const float*)d_in[1];
  const float* b1 = (const float*)d_in[2];
  const float* w2 = (const float*)d_in[3];
  const float* b2 = (const float*)d_in[4];
  const float* w3 = (const float*)d_in[5];
  const float* b3 = (const float*)d_in[6];
  const float* eps = (const float*)d_in[7];
  float* out_action = (float*)d_out;
  float* out_logp = out_action + (size_t)Bsz * Aact;

  char* p = (char*)d_ws;
  auto take = [&](size_t bytes) {
    char* r = p;
    p += (bytes + 255) & ~(size_t)255;
    return r;
  };
  float* v2f = (float*)take((size_t)Bsz * Hd * 4);                 // 32 MB
  float* v3f = (float*)take((size_t)Bsz * Od * 4);                 // 2 MB
  unsigned char* s1pack = (unsigned char*)take((size_t)Bsz * Hd);  // 8 MB
  _Float16* s1cur = (_Float16*)take((size_t)Bsz * Hd * 2);         // 16 MB
  _Float16* s2 = (_Float16*)take((size_t)Bsz * Hd * 2);            // 16 MB
  _Float16* w2p1 = (_Float16*)take((size_t)Hd * Hd * 2);
  _Float16* w2p2 = (_Float16*)take((size_t)Hd * Hd * 2);
  _Float16* w2p3 = (_Float16*)take((size_t)Hd * Hd * 2);
  _Float16* w3p1 = (_Float16*)take((size_t)Od * Hd * 2);
  _Float16* w3p2 = (_Float16*)take((size_t)Od * Hd * 2);
  _Float16* w3p3 = (_Float16*)take((size_t)Od * Hd * 2);

  wsplit_kernel<<<dim3(Hd / 32, Hd / 32), dim3(32, 8), 0, stream>>>(w2, w2p1, w2p2, w2p3, Hd, Hd);
  wsplit_kernel<<<dim3(Od / 32, Hd / 32), dim3(32, 8), 0, stream>>>(w3, w3p1, w3p2, w3p3, Hd, Od);
  x1_kernel<<<dim3(Bsz / 64, Hd / 32), 256, 0, stream>>>(state, w1, b1, s1pack);

  for (int t = 0; t < 8; ++t) {
    expand_kernel<<<(Bsz * Hd / 4) / 256, 256, 0, stream>>>(s1pack, s1cur, t);
    gemm2d_kernel<<<dim3(Bsz / 128, Hd / 64), 256, 0, stream>>>(s1cur, w2p1, w2p2, w2p3,
                                                                b2, v2f, s2, t, w2, s1pack);
    gemm3d_kernel<<<Bsz / 64, 256, 0, stream>>>(s2, w3p1, w3p2, w3p3, b3, v3f, t == 0);
  }

  final_kernel<<<Bsz / 8, 256, 0, stream>>>(v3f, eps, out_action, out_logp);
}

// Round 11
// 2020.211 us; speedup vs baseline: 4.2076x; 4.2076x over previous
//
#include <hip/hip_runtime.h>

typedef _Float16 f16x8 __attribute__((ext_vector_type(8)));
typedef _Float16 f16x4 __attribute__((ext_vector_type(4)));
typedef float    f32x4 __attribute__((ext_vector_type(4)));

typedef const __attribute__((address_space(1))) void* gptr_t;
typedef __attribute__((address_space(3))) void* lptr_t;

__device__ __forceinline__ void gload_lds16(const void* g, void* l) {
  __builtin_amdgcn_global_load_lds((gptr_t)g, (lptr_t)l, 16, 0, 0);
}

constexpr int Bsz  = 8192;
constexpr int Nin  = 128;
constexpr int Hd   = 1024;
constexpr int Aact = 32;
constexpr int Od   = 64;
// OpenBLAS sgemm K-blocking: K=1024 -> blocks [0,384),[384,768),[768,1024),
// C = S1; C += S2; C += S3. Micro-kernel: one fp32 acc, k ascending.
constexpr int KC = 384;
// borderline window (R10-validated: PASSED with this value)
constexpr float DELTA = 2e-5f;

// ---- digit split for exact MFMA: w = d1 + d2*2^-12 + d3*2^-24 + r, |r|<=2^-36.
__global__ void wsplit_kernel(const float* __restrict__ src, _Float16* __restrict__ d1,
                              _Float16* __restrict__ d2, _Float16* __restrict__ d3,
                              int R, int C) {
  __shared__ float tile[32][33];
  int c0 = blockIdx.x * 32, r0 = blockIdx.y * 32;
  for (int i = threadIdx.y; i < 32; i += 8)
    tile[i][threadIdx.x] = src[(size_t)(r0 + i) * C + c0 + threadIdx.x];
  __syncthreads();
  for (int i = threadIdx.y; i < 32; i += 8) {
    float w = tile[threadIdx.x][i];
    float m1 = rintf(w * 2048.0f);
    float q1 = m1 * (1.0f / 2048.0f);
    float r  = w - q1;
    float m2 = rintf(r * 8388608.0f);         // 2^23
    float q2 = m2 * (1.0f / 8388608.0f);
    float r2 = r - q2;
    float m3 = rintf(r2 * 34359738368.0f);    // 2^35
    size_t o = (size_t)(c0 + i) * R + r0 + threadIdx.x;
    d1[o] = (_Float16)q1;
    d2[o] = (_Float16)(m2 * (1.0f / 2048.0f));
    d3[o] = (_Float16)(m3 * (1.0f / 2048.0f));
  }
}

// ---- plain fp32 transpose: src[R][C] -> dst[C][R]. For the replay's
// contiguous-k column access (R10's column-strided loads were the ~1.7ms tail).
__global__ void transpose_f32_kernel(const float* __restrict__ src,
                                     float* __restrict__ dst, int R, int C) {
  __shared__ float tile[32][33];
  int c0 = blockIdx.x * 32, r0 = blockIdx.y * 32;
  for (int i = threadIdx.y; i < 32; i += 8)
    tile[i][threadIdx.x] = src[(size_t)(r0 + i) * C + c0 + threadIdx.x];
  __syncthreads();
  for (int i = threadIdx.y; i < 32; i += 8)
    dst[(size_t)(c0 + i) * R + r0 + threadIdx.x] = tile[threadIdx.x][i];
}

// ---- layer 1: EMULATE np's sgemm (K=128 < KC -> single block): sequential
// fp32 FMA over k ascending, one accumulator. Then the fp32 trajectory
// h = fl(fl(v+x)+b1); v resets to exact 0 -> pack 8 steps' spikes per byte.
__global__ __launch_bounds__(256)
void x1_kernel(const float* __restrict__ state, const float* __restrict__ w1,
               const float* __restrict__ b1, unsigned char* __restrict__ s1pack) {
  __shared__ float sA[64][129];   // [m][k], padded
  __shared__ float sB[128][32];   // [k][n]
  const int m0 = blockIdx.x * 64, n0 = blockIdx.y * 32;
  const int tid = threadIdx.x;
  for (int idx = tid; idx < 64 * 32; idx += 256) {
    int r = idx >> 5, c4 = (idx & 31) << 2;
    float4 v = *(const float4*)(state + (size_t)(m0 + r) * Nin + c4);
    sA[r][c4] = v.x; sA[r][c4 + 1] = v.y; sA[r][c4 + 2] = v.z; sA[r][c4 + 3] = v.w;
  }
  for (int idx = tid; idx < 128 * 8; idx += 256) {
    int r = idx >> 3, c4 = (idx & 7) << 2;
    *(float4*)&sB[r][c4] = *(const float4*)(w1 + (size_t)r * Hd + n0 + c4);
  }
  __syncthreads();
  const int tx = tid & 15, ty = tid >> 4;   // 16x16 threads, micro 4m x 2n
  float acc[4][2] = {};
  for (int k = 0; k < 128; ++k) {           // ASCENDING, single acc: np order
    float a[4], b[2];
#pragma unroll
    for (int i = 0; i < 4; ++i) a[i] = sA[ty * 4 + i][k];
#pragma unroll
    for (int j = 0; j < 2; ++j) b[j] = sB[k][tx * 2 + j];
#pragma unroll
    for (int i = 0; i < 4; ++i)
#pragma unroll
      for (int j = 0; j < 2; ++j) acc[i][j] = __fmaf_rn(a[i], b[j], acc[i][j]);
  }
#pragma unroll
  for (int i = 0; i < 4; ++i)
#pragma unroll
    for (int j = 0; j < 2; ++j) {
      int m = m0 + ty * 4 + i, n = n0 + tx * 2 + j;
      float x = acc[i][j];
      float bb = b1[n];
      float v = 0.0f;
      unsigned bits = 0;
#pragma unroll
      for (int t = 0; t < 8; ++t) {
        float h = __fadd_rn(__fadd_rn(v, x), bb);   // np: (v1 + G1) + b1
        if (h >= 1.0f) { bits |= (1u << t); v = 0.0f; } else { v = h; }
      }
      s1pack[(size_t)m * Hd + n] = (unsigned char)bits;
    }
}

// ---- expand step-t layer-1 spikes to f16 for MFMA A-operand
__global__ void expand_kernel(const unsigned char* __restrict__ pack,
                              _Float16* __restrict__ s1cur, int t) {
  size_t i = (size_t)blockIdx.x * 256 + threadIdx.x;   // over Bsz*Hd/4
  uchar4 p = ((const uchar4*)pack)[i];
  f16x4 s;
  s[0] = (_Float16)(float)((p.x >> t) & 1);
  s[1] = (_Float16)(float)((p.y >> t) & 1);
  s[2] = (_Float16)(float)((p.z >> t) & 1);
  s[3] = (_Float16)(float)((p.w >> t) & 1);
  ((f16x4*)s1cur)[i] = s;
}

// np-faithful G at step tau for neuron column `col` (= w2tf + n*Hd, contiguous
// in k): masked ASCENDING fp32 sum (branchless +0.0f is exact-equivalent to
// skip), partials folded at KC boundaries exactly as OpenBLAS. 8-wide batched
// loads: column (4KB) + prow (1KB) are L1-resident after tau=0 -> ~25us/neuron
// vs R10's ~1ms column-strided version.
__device__ __noinline__ float np_gemm2_col(const unsigned char* __restrict__ prow,
                                           const float* __restrict__ col, int tau) {
  float G = 0.0f;
#pragma unroll
  for (int blk = 0; blk < 3; ++blk) {
    int kb = blk * KC;
    int kend = (blk == 2) ? Hd : (kb + KC);   // 384, 768, 1024
    float S = 0.0f;
    for (int k = kb; k < kend; k += 8) {
      float4 wa = *(const float4*)(col + k);
      float4 wb = *(const float4*)(col + k + 4);
      unsigned b0 = *(const unsigned*)(prow + k);
      unsigned b1 = *(const unsigned*)(prow + k + 4);
      S = __fadd_rn(S, ((b0 >> tau) & 1)        ? wa.x : 0.0f);
      S = __fadd_rn(S, ((b0 >> (8 + tau)) & 1)  ? wa.y : 0.0f);
      S = __fadd_rn(S, ((b0 >> (16 + tau)) & 1) ? wa.z : 0.0f);
      S = __fadd_rn(S, ((b0 >> (24 + tau)) & 1) ? wa.w : 0.0f);
      S = __fadd_rn(S, ((b1 >> tau) & 1)        ? wb.x : 0.0f);
      S = __fadd_rn(S, ((b1 >> (8 + tau)) & 1)  ? wb.y : 0.0f);
      S = __fadd_rn(S, ((b1 >> (16 + tau)) & 1) ? wb.z : 0.0f);
      S = __fadd_rn(S, ((b1 >> (24 + tau)) & 1) ? wb.w : 0.0f);
    }
    G = (blk == 0) ? S : __fadd_rn(G, S);
  }
  return G;
}

// ---- GEMM2: exact 3-digit MFMA decides non-borderline spikes (provably = np);
// borderline (|h-1| < DELTA): replay this neuron's full v2 recursion in
// np's summation order from s1pack + transposed fp32 w2.
__global__ __launch_bounds__(256, 2)
void gemm2d_kernel(const _Float16* __restrict__ s1, const _Float16* __restrict__ w2d1,
                   const _Float16* __restrict__ w2d2, const _Float16* __restrict__ w2d3,
                   const float* __restrict__ b2, float* __restrict__ v2,
                   _Float16* __restrict__ s2, int t,
                   const float* __restrict__ w2tf,
                   const unsigned char* __restrict__ s1pack) {
  constexpr int K = Hd;
  __shared__ _Float16 lA[128 * 32], lB1[64 * 32], lB2[64 * 32], lB3[64 * 32];
  const int tid = threadIdx.x;
  const int m0 = blockIdx.x * 128, n0 = blockIdx.y * 64;
  const int wave = tid >> 6, lane = tid & 63, l15 = lane & 15, quad = lane >> 4;
  f32x4 acc[2][4][3] = {};
  for (int k0 = 0; k0 < K; k0 += 32) {
    __syncthreads();
#pragma unroll
    for (int it = 0; it < 2; ++it) {
      int slot = it * 256 + tid;
      int row = slot >> 2, kc = (slot & 3) << 3;
      gload_lds16(s1 + (size_t)(m0 + row) * K + k0 + kc, lA + slot * 8);
    }
    {
      int row = tid >> 2, kc = (tid & 3) << 3;
      size_t go = (size_t)(n0 + row) * K + k0 + kc;
      gload_lds16(w2d1 + go, lB1 + tid * 8);
      gload_lds16(w2d2 + go, lB2 + tid * 8);
      gload_lds16(w2d3 + go, lB3 + tid * 8);
    }
    __syncthreads();
    f16x8 af[2], bf[4][3];
#pragma unroll
    for (int i = 0; i < 2; ++i)
      af[i] = *(const f16x8*)(lA + (wave * 32 + i * 16 + l15) * 32 + quad * 8);
#pragma unroll
    for (int j = 0; j < 4; ++j) {
      int off = (j * 16 + l15) * 32 + quad * 8;
      bf[j][0] = *(const f16x8*)(lB1 + off);
      bf[j][1] = *(const f16x8*)(lB2 + off);
      bf[j][2] = *(const f16x8*)(lB3 + off);
    }
#pragma unroll
    for (int i = 0; i < 2; ++i)
#pragma unroll
      for (int j = 0; j < 4; ++j)
#pragma unroll
        for (int d = 0; d < 3; ++d)
          acc[i][j][d] = __builtin_amdgcn_mfma_f32_16x16x32_f16(af[i], bf[j][d], acc[i][j][d], 0, 0, 0);
  }
#pragma unroll
  for (int i = 0; i < 2; ++i)
#pragma unroll
    for (int j = 0; j < 4; ++j) {
      int n = n0 + j * 16 + l15;
      float bb = b2[n];
#pragma unroll
      for (int r = 0; r < 4; ++r) {
        int m = m0 + wave * 32 + i * 16 + quad * 4 + r;
        size_t idx = (size_t)m * Hd + n;
        double ge = (double)acc[i][j][0][r]
                  + (double)acc[i][j][1][r] * (1.0 / 4096.0)
                  + (double)acc[i][j][2][r] * (1.0 / 16777216.0);
        float G = (float)ge;                       // cr-fp32 of exact gemm
        float vp = (t == 0) ? 0.0f : v2[idx];
        float h = __fadd_rn(__fadd_rn(vp, G), bb); // np: (v2 + G) + b2
        bool sp;
        float vnew;
        if (__builtin_fabsf(h - 1.0f) >= DELTA) {  // decision certain == np
          sp = (h >= 1.0f);
          vnew = sp ? 0.0f : h;
        } else {
          // rare: replay np's v2 recursion for this neuron from step 0
          const unsigned char* prow = s1pack + (size_t)m * Hd;
          const float* col = w2tf + (size_t)n * Hd;
          float v = 0.0f;
          sp = false;
          for (int tau = 0; tau <= t; ++tau) {
            float Gn = np_gemm2_col(prow, col, tau);
            float hn = __fadd_rn(__fadd_rn(v, Gn), bb);
            sp = (hn >= 1.0f);
            v = sp ? 0.0f : hn;
          }
          vnew = v;
        }
        v2[idx] = vnew;
        s2[idx] = (_Float16)(sp ? 1.0f : 0.0f);
      }
    }
}

// ---- GEMM3 (exact 3-digit) + fp32-replicated LIF
__global__ __launch_bounds__(256, 2)
void gemm3d_kernel(const _Float16* __restrict__ s2, const _Float16* __restrict__ w3d1,
                   const _Float16* __restrict__ w3d2, const _Float16* __restrict__ w3d3,
                   const float* __restrict__ b3, float* __restrict__ v3, int first) {
  constexpr int K = Hd;
  __shared__ _Float16 lA[64 * 32], lB1[64 * 32], lB2[64 * 32], lB3[64 * 32];
  const int tid = threadIdx.x;
  const int m0 = blockIdx.x * 64;
  const int wave = tid >> 6, lane = tid & 63, l15 = lane & 15, quad = lane >> 4;
  f32x4 acc[4][3] = {};
  for (int k0 = 0; k0 < K; k0 += 32) {
    __syncthreads();
    {
      int row = tid >> 2, kc = (tid & 3) << 3;
      gload_lds16(s2 + (size_t)(m0 + row) * K + k0 + kc, lA + tid * 8);
      size_t go = (size_t)row * K + k0 + kc;
      gload_lds16(w3d1 + go, lB1 + tid * 8);
      gload_lds16(w3d2 + go, lB2 + tid * 8);
      gload_lds16(w3d3 + go, lB3 + tid * 8);
    }
    __syncthreads();
    f16x8 af = *(const f16x8*)(lA + (wave * 16 + l15) * 32 + quad * 8);
    f16x8 bf[4][3];
#pragma unroll
    for (int j = 0; j < 4; ++j) {
      int off = (j * 16 + l15) * 32 + quad * 8;
      bf[j][0] = *(const f16x8*)(lB1 + off);
      bf[j][1] = *(const f16x8*)(lB2 + off);
      bf[j][2] = *(const f16x8*)(lB3 + off);
    }
#pragma unroll
    for (int j = 0; j < 4; ++j)
#pragma unroll
      for (int d = 0; d < 3; ++d)
        acc[j][d] = __builtin_amdgcn_mfma_f32_16x16x32_f16(af, bf[j][d], acc[j][d], 0, 0, 0);
  }
#pragma unroll
  for (int j = 0; j < 4; ++j) {
    int n = j * 16 + l15;
    float bb = b3[n];
#pragma unroll
    for (int r = 0; r < 4; ++r) {
      int m = m0 + wave * 16 + quad * 4 + r;
      size_t idx = (size_t)m * Od + n;
      double ge = (double)acc[j][0][r]
                + (double)acc[j][1][r] * (1.0 / 4096.0)
                + (double)acc[j][2][r] * (1.0 / 16777216.0);
      float x3 = __fadd_rn((float)ge, bb);
      float vp = first ? 0.0f : v3[idx];
      float d  = __fsub_rn(x3, vp);
      v3[idx]  = __fadd_rn(vp, __fmul_rn(d, 0.5f));
    }
  }
}

// ---- final: fp32 op sequence as numpy; tanh clamped to +/-1 at |z| >=
// 7.90531111 (R8-validated: np's tanh is exactly +/-1 on all live band coords)
__global__ void final_kernel(const float* __restrict__ v3, const float* __restrict__ eps,
                             float* __restrict__ action, float* __restrict__ logp) {
  int tid = threadIdx.x;
  int row = blockIdx.x * 8 + (tid >> 5);
  int j = tid & 31;
  float mu = v3[(size_t)row * Od + j];
  float ls = v3[(size_t)row * Od + 32 + j];
  ls = fminf(fmaxf(ls, -20.0f), 2.0f);
  float sd = (float)exp((double)ls);
  float e  = eps[(size_t)row * Aact + j];
  float z  = __fadd_rn(mu, __fmul_rn(sd, e));
  float a;
  if (__builtin_fabsf(z) >= 7.90531111f) a = __builtin_copysignf(1.0f, z);
  else                                   a = (float)tanh((double)z);
  float aa = __fmul_rn(a, a);
  float u  = __fadd_rn(__fsub_rn(1.0f, aa), 1e-7f);
  float lg = (float)log((double)u);
  float l  = __fmul_rn(__fmul_rn(-0.5f, e), e);
  l = __fsub_rn(l, ls);
  l = __fsub_rn(l, 0.9189385332046727f);
  float term = __fsub_rn(l, lg);
  action[(size_t)row * Aact + j] = a;
  double lp = (double)term;
#pragma unroll
  for (int w = 16; w >= 1; w >>= 1) lp += __shfl_xor(lp, w);
  if (j == 0) logp[row] = (float)lp;
}

extern "C" void kernel_launch(void* const* d_in, const int* in_sizes, int n_in,
                              void* d_out, int out_size, void* d_ws, size_t ws_size,
                              hipStream_t stream) {
  const float* state = (const float*)d_in[0];
  const float* w1 = (const float*)d_in[1];
  const float* b1 = (const float*)d_in[2];
  const float* w2 = (const float*)d_in[3];
  const float* b2 = (const float*)d_in[4];
  const float* w3 = (const float*)d_in[5];
  const float* b3 = (const float*)d_in[6];
  const float* eps = (const float*)d_in[7];
  float* out_action = (float*)d_out;
  float* out_logp = out_action + (size_t)Bsz * Aact;

  char* p = (char*)d_ws;
  auto take = [&](size_t bytes) {
    char* r = p;
    p += (bytes + 255) & ~(size_t)255;
    return r;
  };
  float* v2f = (float*)take((size_t)Bsz * Hd * 4);                 // 32 MB
  float* v3f = (float*)take((size_t)Bsz * Od * 4);                 // 2 MB
  unsigned char* s1pack = (unsigned char*)take((size_t)Bsz * Hd);  // 8 MB
  _Float16* s1cur = (_Float16*)take((size_t)Bsz * Hd * 2);         // 16 MB
  _Float16* s2 = (_Float16*)take((size_t)Bsz * Hd * 2);            // 16 MB
  _Float16* w2p1 = (_Float16*)take((size_t)Hd * Hd * 2);
  _Float16* w2p2 = (_Float16*)take((size_t)Hd * Hd * 2);
  _Float16* w2p3 = (_Float16*)take((size_t)Hd * Hd * 2);
  _Float16* w3p1 = (_Float16*)take((size_t)Od * Hd * 2);
  _Float16* w3p2 = (_Float16*)take((size_t)Od * Hd * 2);
  _Float16* w3p3 = (_Float16*)take((size_t)Od * Hd * 2);
  float* w2tf = (float*)take((size_t)Hd * Hd * 4);                 // 4 MB

  wsplit_kernel<<<dim3(Hd / 32, Hd / 32), dim3(32, 8), 0, stream>>>(w2, w2p1, w2p2, w2p3, Hd, Hd);
  wsplit_kernel<<<dim3(Od / 32, Hd / 32), dim3(32, 8), 0, stream>>>(w3, w3p1, w3p2, w3p3, Hd, Od);
  transpose_f32_kernel<<<dim3(Hd / 32, Hd / 32), dim3(32, 8), 0, stream>>>(w2, w2tf, Hd, Hd);
  x1_kernel<<<dim3(Bsz / 64, Hd / 32), 256, 0, stream>>>(state, w1, b1, s1pack);

  for (int t = 0; t < 8; ++t) {
    expand_kernel<<<(Bsz * Hd / 4) / 256, 256, 0, stream>>>(s1pack, s1cur, t);
    gemm2d_kernel<<<dim3(Bsz / 128, Hd / 64), 256, 0, stream>>>(s1cur, w2p1, w2p2, w2p3,
                                                                b2, v2f, s2, t, w2tf, s1pack);
    gemm3d_kernel<<<Bsz / 64, 256, 0, stream>>>(s2, w3p1, w3p2, w3p3, b3, v3f, t == 0);
  }

  final_kernel<<<Bsz / 8, 256, 0, stream>>>(v3f, eps, out_action, out_logp);
}

// Round 12
// 1325.487 us; speedup vs baseline: 6.4129x; 1.5241x over previous
//
#include <hip/hip_runtime.h>

typedef _Float16 f16x8 __attribute__((ext_vector_type(8)));
typedef _Float16 f16x4 __attribute__((ext_vector_type(4)));
typedef float    f32x4 __attribute__((ext_vector_type(4)));

typedef const __attribute__((address_space(1))) void* gptr_t;
typedef __attribute__((address_space(3))) void* lptr_t;

__device__ __forceinline__ void gload_lds16(const void* g, void* l) {
  __builtin_amdgcn_global_load_lds((gptr_t)g, (lptr_t)l, 16, 0, 0);
}

constexpr int Bsz  = 8192;
constexpr int Nin  = 128;
constexpr int Hd   = 1024;
constexpr int Aact = 32;
constexpr int Od   = 64;
// OpenBLAS sgemm K-blocking: K=1024 -> [0,384),[384,768),[768,1024);
// C = S1; C += S2; C += S3. Micro-kernel: one fp32 acc, k ascending.
constexpr int KC = 384;
// borderline window (R10/R11-validated: PASSED, absmax 0.3125)
constexpr float DELTA = 2e-5f;
constexpr unsigned WCAP = 65536;   // worklist capacity (observed ~1e2/step)

// ---- digit split for exact MFMA: w = d1 + d2*2^-12 + d3*2^-24 + r, |r|<=2^-36.
__global__ void wsplit_kernel(const float* __restrict__ src, _Float16* __restrict__ d1,
                              _Float16* __restrict__ d2, _Float16* __restrict__ d3,
                              int R, int C) {
  __shared__ float tile[32][33];
  int c0 = blockIdx.x * 32, r0 = blockIdx.y * 32;
  for (int i = threadIdx.y; i < 32; i += 8)
    tile[i][threadIdx.x] = src[(size_t)(r0 + i) * C + c0 + threadIdx.x];
  __syncthreads();
  for (int i = threadIdx.y; i < 32; i += 8) {
    float w = tile[threadIdx.x][i];
    float m1 = rintf(w * 2048.0f);
    float q1 = m1 * (1.0f / 2048.0f);
    float r  = w - q1;
    float m2 = rintf(r * 8388608.0f);         // 2^23
    float q2 = m2 * (1.0f / 8388608.0f);
    float r2 = r - q2;
    float m3 = rintf(r2 * 34359738368.0f);    // 2^35
    size_t o = (size_t)(c0 + i) * R + r0 + threadIdx.x;
    d1[o] = (_Float16)q1;
    d2[o] = (_Float16)(m2 * (1.0f / 2048.0f));
    d3[o] = (_Float16)(m3 * (1.0f / 2048.0f));
  }
}

// ---- fp32 transpose: src[R][C] -> dst[C][R] (replay column contiguity)
__global__ void transpose_f32_kernel(const float* __restrict__ src,
                                     float* __restrict__ dst, int R, int C) {
  __shared__ float tile[32][33];
  int c0 = blockIdx.x * 32, r0 = blockIdx.y * 32;
  for (int i = threadIdx.y; i < 32; i += 8)
    tile[i][threadIdx.x] = src[(size_t)(r0 + i) * C + c0 + threadIdx.x];
  __syncthreads();
  for (int i = threadIdx.y; i < 32; i += 8)
    dst[(size_t)(c0 + i) * R + r0 + threadIdx.x] = tile[threadIdx.x][i];
}

// ---- layer 1: EMULATE np's sgemm (K=128 single block, ascending fp32 FMA),
// then the fp32 trajectory; v resets to exact 0 -> pack 8 steps' spikes/byte.
__global__ __launch_bounds__(256)
void x1_kernel(const float* __restrict__ state, const float* __restrict__ w1,
               const float* __restrict__ b1, unsigned char* __restrict__ s1pack) {
  __shared__ float sA[64][129];
  __shared__ float sB[128][32];
  const int m0 = blockIdx.x * 64, n0 = blockIdx.y * 32;
  const int tid = threadIdx.x;
  for (int idx = tid; idx < 64 * 32; idx += 256) {
    int r = idx >> 5, c4 = (idx & 31) << 2;
    float4 v = *(const float4*)(state + (size_t)(m0 + r) * Nin + c4);
    sA[r][c4] = v.x; sA[r][c4 + 1] = v.y; sA[r][c4 + 2] = v.z; sA[r][c4 + 3] = v.w;
  }
  for (int idx = tid; idx < 128 * 8; idx += 256) {
    int r = idx >> 3, c4 = (idx & 7) << 2;
    *(float4*)&sB[r][c4] = *(const float4*)(w1 + (size_t)r * Hd + n0 + c4);
  }
  __syncthreads();
  const int tx = tid & 15, ty = tid >> 4;
  float acc[4][2] = {};
  for (int k = 0; k < 128; ++k) {           // ASCENDING, single acc: np order
    float a[4], b[2];
#pragma unroll
    for (int i = 0; i < 4; ++i) a[i] = sA[ty * 4 + i][k];
#pragma unroll
    for (int j = 0; j < 2; ++j) b[j] = sB[k][tx * 2 + j];
#pragma unroll
    for (int i = 0; i < 4; ++i)
#pragma unroll
      for (int j = 0; j < 2; ++j) acc[i][j] = __fmaf_rn(a[i], b[j], acc[i][j]);
  }
#pragma unroll
  for (int i = 0; i < 4; ++i)
#pragma unroll
    for (int j = 0; j < 2; ++j) {
      int m = m0 + ty * 4 + i, n = n0 + tx * 2 + j;
      float x = acc[i][j];
      float bb = b1[n];
      float v = 0.0f;
      unsigned bits = 0;
#pragma unroll
      for (int t = 0; t < 8; ++t) {
        float h = __fadd_rn(__fadd_rn(v, x), bb);   // np: (v1 + G1) + b1
        if (h >= 1.0f) { bits |= (1u << t); v = 0.0f; } else { v = h; }
      }
      s1pack[(size_t)m * Hd + n] = (unsigned char)bits;
    }
}

// build f16 A-fragment from 8 spike bytes (bit t) — identical values to the
// old expand_kernel's f16 output, so MFMA inputs are bit-identical.
__device__ __forceinline__ f16x8 frag_from_bits(const unsigned char* ap, int t) {
  unsigned d0 = *(const unsigned*)ap;
  unsigned d1 = *(const unsigned*)(ap + 4);
  f16x8 a;
  a[0] = (_Float16)((d0 >> t) & 1u);
  a[1] = (_Float16)((d0 >> (8 + t)) & 1u);
  a[2] = (_Float16)((d0 >> (16 + t)) & 1u);
  a[3] = (_Float16)((d0 >> (24 + t)) & 1u);
  a[4] = (_Float16)((d1 >> t) & 1u);
  a[5] = (_Float16)((d1 >> (8 + t)) & 1u);
  a[6] = (_Float16)((d1 >> (16 + t)) & 1u);
  a[7] = (_Float16)((d1 >> (24 + t)) & 1u);
  return a;
}

// ---- GEMM2: exact 3-digit MFMA decides non-borderline spikes (== np);
// borderline (|h-1| < DELTA): append to worklist, fixup_kernel replays.
// A-operand staged directly from s1pack bytes (expand fused away).
__global__ __launch_bounds__(256, 2)
void gemm2d_kernel(const unsigned char* __restrict__ s1pack,
                   const _Float16* __restrict__ w2d1,
                   const _Float16* __restrict__ w2d2, const _Float16* __restrict__ w2d3,
                   const float* __restrict__ b2, float* __restrict__ v2,
                   _Float16* __restrict__ s2, int t,
                   unsigned* __restrict__ wcnt, unsigned* __restrict__ wlist) {
  constexpr int K = Hd;
  __shared__ __align__(16) unsigned char lAb[128 * 32];
  __shared__ _Float16 lB1[64 * 32], lB2[64 * 32], lB3[64 * 32];
  const int tid = threadIdx.x;
  const int m0 = blockIdx.x * 128, n0 = blockIdx.y * 64;
  const int wave = tid >> 6, lane = tid & 63, l15 = lane & 15, quad = lane >> 4;
  f32x4 acc[2][4][3] = {};
  for (int k0 = 0; k0 < K; k0 += 32) {
    __syncthreads();
    {
      int arow = tid >> 1, akc = (tid & 1) << 4;   // 128 rows x 32 bytes
      gload_lds16(s1pack + (size_t)(m0 + arow) * Hd + k0 + akc, lAb + arow * 32 + akc);
      int row = tid >> 2, kc = (tid & 3) << 3;
      size_t go = (size_t)(n0 + row) * K + k0 + kc;
      gload_lds16(w2d1 + go, lB1 + tid * 8);
      gload_lds16(w2d2 + go, lB2 + tid * 8);
      gload_lds16(w2d3 + go, lB3 + tid * 8);
    }
    __syncthreads();
    f16x8 af[2], bf[4][3];
#pragma unroll
    for (int i = 0; i < 2; ++i)
      af[i] = frag_from_bits(lAb + (wave * 32 + i * 16 + l15) * 32 + quad * 8, t);
#pragma unroll
    for (int j = 0; j < 4; ++j) {
      int off = (j * 16 + l15) * 32 + quad * 8;
      bf[j][0] = *(const f16x8*)(lB1 + off);
      bf[j][1] = *(const f16x8*)(lB2 + off);
      bf[j][2] = *(const f16x8*)(lB3 + off);
    }
#pragma unroll
    for (int i = 0; i < 2; ++i)
#pragma unroll
      for (int j = 0; j < 4; ++j)
#pragma unroll
        for (int d = 0; d < 3; ++d)
          acc[i][j][d] = __builtin_amdgcn_mfma_f32_16x16x32_f16(af[i], bf[j][d], acc[i][j][d], 0, 0, 0);
  }
#pragma unroll
  for (int i = 0; i < 2; ++i)
#pragma unroll
    for (int j = 0; j < 4; ++j) {
      int n = n0 + j * 16 + l15;
      float bb = b2[n];
#pragma unroll
      for (int r = 0; r < 4; ++r) {
        int m = m0 + wave * 32 + i * 16 + quad * 4 + r;
        size_t idx = (size_t)m * Hd + n;
        double ge = (double)acc[i][j][0][r]
                  + (double)acc[i][j][1][r] * (1.0 / 4096.0)
                  + (double)acc[i][j][2][r] * (1.0 / 16777216.0);
        float G = (float)ge;                       // cr-fp32 of exact gemm
        float vp = (t == 0) ? 0.0f : v2[idx];
        float h = __fadd_rn(__fadd_rn(vp, G), bb); // np: (v2 + G) + b2
        if (__builtin_fabsf(h - 1.0f) < DELTA) {   // rare: defer to fixup
          unsigned pos = atomicAdd(wcnt, 1u);
          if (pos < WCAP) wlist[pos] = (unsigned)idx;
        }
        bool sp = (h >= 1.0f);                     // provisional (certain if
        v2[idx] = sp ? 0.0f : h;                   //  not on worklist)
        s2[idx] = (_Float16)(sp ? 1.0f : 0.0f);
      }
    }
}

// ---- fixup: replay np's v2 recursion for worklist sites. 3 lanes per site
// (one per KC block) scan the w2 column once computing all 8 tau partial
// sums (branchless +0.0f == skip, ascending k: bit-identical to R11's
// validated inline replay), shuffle-combine in np's fold order, lane blk==0
// runs the recursion and patches v2/s2.
__global__ __launch_bounds__(256)
void fixup_kernel(const unsigned* __restrict__ wcnt, const unsigned* __restrict__ wlist,
                  const unsigned char* __restrict__ s1pack, const float* __restrict__ w2tf,
                  const float* __restrict__ b2, float* __restrict__ v2,
                  _Float16* __restrict__ s2, int t) {
  unsigned cnt = *wcnt;
  if (cnt > WCAP) cnt = WCAP;
  const int tid = threadIdx.x;
  const int lane = tid & 63;
  const int sl = lane / 3, blk3 = lane - sl * 3;     // 21 sites/wave, lane 63 idle
  const int wid = blockIdx.x * (blockDim.x >> 6) + (tid >> 6);
  const int nwaves = gridDim.x * (blockDim.x >> 6);
  for (unsigned base = (unsigned)wid * 21u; base < cnt; base += (unsigned)nwaves * 21u) {
    unsigned site = base + (unsigned)sl;
    bool act = (sl < 21) && (site < cnt);
    unsigned idx = act ? wlist[site] : 0u;
    int m = (int)(idx >> 10), n = (int)(idx & 1023u);
    const unsigned char* prow = s1pack + ((size_t)m << 10);
    const float* col = w2tf + ((size_t)n << 10);
    int kb = blk3 * KC;
    int kend = (blk3 == 2) ? Hd : kb + KC;
    float S[8] = {};
    if (act) {
      for (int k = kb; k < kend; k += 8) {
        float4 wa = *(const float4*)(col + k);
        float4 wb = *(const float4*)(col + k + 4);
        unsigned b0 = *(const unsigned*)(prow + k);
        unsigned b1 = *(const unsigned*)(prow + k + 4);
#pragma unroll
        for (int tau = 0; tau < 8; ++tau) {
          S[tau] = __fadd_rn(S[tau], ((b0 >> tau) & 1)        ? wa.x : 0.0f);
          S[tau] = __fadd_rn(S[tau], ((b0 >> (8 + tau)) & 1)  ? wa.y : 0.0f);
          S[tau] = __fadd_rn(S[tau], ((b0 >> (16 + tau)) & 1) ? wa.z : 0.0f);
          S[tau] = __fadd_rn(S[tau], ((b0 >> (24 + tau)) & 1) ? wa.w : 0.0f);
          S[tau] = __fadd_rn(S[tau], ((b1 >> tau) & 1)        ? wb.x : 0.0f);
          S[tau] = __fadd_rn(S[tau], ((b1 >> (8 + tau)) & 1)  ? wb.y : 0.0f);
          S[tau] = __fadd_rn(S[tau], ((b1 >> (16 + tau)) & 1) ? wb.z : 0.0f);
          S[tau] = __fadd_rn(S[tau], ((b1 >> (24 + tau)) & 1) ? wb.w : 0.0f);
        }
      }
    }
    float G[8];
#pragma unroll
    for (int tau = 0; tau < 8; ++tau) {
      float sB = __shfl(S[tau], lane + 1);
      float sC = __shfl(S[tau], lane + 2);
      G[tau] = __fadd_rn(__fadd_rn(S[tau], sB), sC);  // np fold: (S1+S2)+S3
    }
    if (act && blk3 == 0) {
      float bb = b2[n];
      float v = 0.0f;
      bool sp = false;
      for (int tau = 0; tau <= t; ++tau) {
        float h = __fadd_rn(__fadd_rn(v, G[tau]), bb);
        sp = (h >= 1.0f);
        v = sp ? 0.0f : h;
      }
      v2[idx] = v;
      s2[idx] = (_Float16)(sp ? 1.0f : 0.0f);
    }
  }
}

// ---- GEMM3 (exact 3-digit) + fp32-replicated LIF
__global__ __launch_bounds__(256, 2)
void gemm3d_kernel(const _Float16* __restrict__ s2, const _Float16* __restrict__ w3d1,
                   const _Float16* __restrict__ w3d2, const _Float16* __restrict__ w3d3,
                   const float* __restrict__ b3, float* __restrict__ v3, int first) {
  constexpr int K = Hd;
  __shared__ _Float16 lA[64 * 32], lB1[64 * 32], lB2[64 * 32], lB3[64 * 32];
  const int tid = threadIdx.x;
  const int m0 = blockIdx.x * 64;
  const int wave = tid >> 6, lane = tid & 63, l15 = lane & 15, quad = lane >> 4;
  f32x4 acc[4][3] = {};
  for (int k0 = 0; k0 < K; k0 += 32) {
    __syncthreads();
    {
      int row = tid >> 2, kc = (tid & 3) << 3;
      gload_lds16(s2 + (size_t)(m0 + row) * K + k0 + kc, lA + tid * 8);
      size_t go = (size_t)row * K + k0 + kc;
      gload_lds16(w3d1 + go, lB1 + tid * 8);
      gload_lds16(w3d2 + go, lB2 + tid * 8);
      gload_lds16(w3d3 + go, lB3 + tid * 8);
    }
    __syncthreads();
    f16x8 af = *(const f16x8*)(lA + (wave * 16 + l15) * 32 + quad * 8);
    f16x8 bf[4][3];
#pragma unroll
    for (int j = 0; j < 4; ++j) {
      int off = (j * 16 + l15) * 32 + quad * 8;
      bf[j][0] = *(const f16x8*)(lB1 + off);
      bf[j][1] = *(const f16x8*)(lB2 + off);
      bf[j][2] = *(const f16x8*)(lB3 + off);
    }
#pragma unroll
    for (int j = 0; j < 4; ++j)
#pragma unroll
      for (int d = 0; d < 3; ++d)
        acc[j][d] = __builtin_amdgcn_mfma_f32_16x16x32_f16(af, bf[j][d], acc[j][d], 0, 0, 0);
  }
#pragma unroll
  for (int j = 0; j < 4; ++j) {
    int n = j * 16 + l15;
    float bb = b3[n];
#pragma unroll
    for (int r = 0; r < 4; ++r) {
      int m = m0 + wave * 16 + quad * 4 + r;
      size_t idx = (size_t)m * Od + n;
      double ge = (double)acc[j][0][r]
                + (double)acc[j][1][r] * (1.0 / 4096.0)
                + (double)acc[j][2][r] * (1.0 / 16777216.0);
      float x3 = __fadd_rn((float)ge, bb);
      float vp = first ? 0.0f : v3[idx];
      float d  = __fsub_rn(x3, vp);
      v3[idx]  = __fadd_rn(vp, __fmul_rn(d, 0.5f));
    }
  }
}

// ---- final: fp32 op sequence as numpy; tanh clamped at |z| >= 7.90531111
// (R8-validated: np's tanh is exactly +/-1 on all live band coords)
__global__ void final_kernel(const float* __restrict__ v3, const float* __restrict__ eps,
                             float* __restrict__ action, float* __restrict__ logp) {
  int tid = threadIdx.x;
  int row = blockIdx.x * 8 + (tid >> 5);
  int j = tid & 31;
  float mu = v3[(size_t)row * Od + j];
  float ls = v3[(size_t)row * Od + 32 + j];
  ls = fminf(fmaxf(ls, -20.0f), 2.0f);
  float sd = (float)exp((double)ls);
  float e  = eps[(size_t)row * Aact + j];
  float z  = __fadd_rn(mu, __fmul_rn(sd, e));
  float a;
  if (__builtin_fabsf(z) >= 7.90531111f) a = __builtin_copysignf(1.0f, z);
  else                                   a = (float)tanh((double)z);
  float aa = __fmul_rn(a, a);
  float u  = __fadd_rn(__fsub_rn(1.0f, aa), 1e-7f);
  float lg = (float)log((double)u);
  float l  = __fmul_rn(__fmul_rn(-0.5f, e), e);
  l = __fsub_rn(l, ls);
  l = __fsub_rn(l, 0.9189385332046727f);
  float term = __fsub_rn(l, lg);
  action[(size_t)row * Aact + j] = a;
  double lp = (double)term;
#pragma unroll
  for (int w = 16; w >= 1; w >>= 1) lp += __shfl_xor(lp, w);
  if (j == 0) logp[row] = (float)lp;
}

extern "C" void kernel_launch(void* const* d_in, const int* in_sizes, int n_in,
                              void* d_out, int out_size, void* d_ws, size_t ws_size,
                              hipStream_t stream) {
  const float* state = (const float*)d_in[0];
  const float* w1 = (const float*)d_in[1];
  const float* b1 = (const float*)d_in[2];
  const float* w2 = (const float*)d_in[3];
  const float* b2 = (const float*)d_in[4];
  const float* w3 = (const float*)d_in[5];
  const float* b3 = (const float*)d_in[6];
  const float* eps = (const float*)d_in[7];
  float* out_action = (float*)d_out;
  float* out_logp = out_action + (size_t)Bsz * Aact;

  char* p = (char*)d_ws;
  auto take = [&](size_t bytes) {
    char* r = p;
    p += (bytes + 255) & ~(size_t)255;
    return r;
  };
  float* v2f = (float*)take((size_t)Bsz * Hd * 4);                 // 32 MB
  float* v3f = (float*)take((size_t)Bsz * Od * 4);                 // 2 MB
  unsigned char* s1pack = (unsigned char*)take((size_t)Bsz * Hd);  // 8 MB
  _Float16* s2 = (_Float16*)take((size_t)Bsz * Hd * 2);            // 16 MB
  _Float16* w2p1 = (_Float16*)take((size_t)Hd * Hd * 2);
  _Float16* w2p2 = (_Float16*)take((size_t)Hd * Hd * 2);
  _Float16* w2p3 = (_Float16*)take((size_t)Hd * Hd * 2);
  _Float16* w3p1 = (_Float16*)take((size_t)Od * Hd * 2);
  _Float16* w3p2 = (_Float16*)take((size_t)Od * Hd * 2);
  _Float16* w3p3 = (_Float16*)take((size_t)Od * Hd * 2);
  float* w2tf = (float*)take((size_t)Hd * Hd * 4);                 // 4 MB
  unsigned* wcnt = (unsigned*)take(8 * 4);                         // 8 counters
  unsigned* wlist = (unsigned*)take((size_t)WCAP * 4);             // 256 KB

  wsplit_kernel<<<dim3(Hd / 32, Hd / 32), dim3(32, 8), 0, stream>>>(w2, w2p1, w2p2, w2p3, Hd, Hd);
  wsplit_kernel<<<dim3(Od / 32, Hd / 32), dim3(32, 8), 0, stream>>>(w3, w3p1, w3p2, w3p3, Hd, Od);
  transpose_f32_kernel<<<dim3(Hd / 32, Hd / 32), dim3(32, 8), 0, stream>>>(w2, w2tf, Hd, Hd);
  x1_kernel<<<dim3(Bsz / 64, Hd / 32), 256, 0, stream>>>(state, w1, b1, s1pack);
  hipMemsetAsync(wcnt, 0, 8 * 4, stream);

  for (int t = 0; t < 8; ++t) {
    gemm2d_kernel<<<dim3(Bsz / 128, Hd / 64), 256, 0, stream>>>(s1pack, w2p1, w2p2, w2p3,
                                                                b2, v2f, s2, t,
                                                                wcnt + t, wlist);
    fixup_kernel<<<32, 256, 0, stream>>>(wcnt + t, wlist, s1pack, w2tf, b2, v2f, s2, t);
    gemm3d_kernel<<<Bsz / 64, 256, 0, stream>>>(s2, w3p1, w3p2, w3p3, b3, v3f, t == 0);
  }

  final_kernel<<<Bsz / 8, 256, 0, stream>>>(v3f, eps, out_action, out_logp);
}